// Round 4
// baseline (1134.218 us; speedup 1.0000x reference)
//
#include <hip/hip_runtime.h>
#include <stdint.h>

#define T_TOKENS 8192
#define D_DIM 1024
#define I_DIM 2816
#define E_NUM 16
#define N_SLOTS 16384

typedef float f32x4 __attribute__((ext_vector_type(4)));
typedef short s16x8 __attribute__((ext_vector_type(8)));
typedef short s16x4 __attribute__((ext_vector_type(4)));
typedef unsigned short u16;
typedef unsigned int u32;

__device__ __forceinline__ u16 f2bf(float f) {
  u32 u = __builtin_bit_cast(u32, f);
  u = (u + 0x7FFFu + ((u >> 16) & 1u)) >> 16;
  return (u16)u;
}
__device__ __forceinline__ u32 pack2(float a, float b) {
  return (u32)f2bf(a) | ((u32)f2bf(b) << 16);
}
__device__ __forceinline__ void async_load16(const void* g, void* l) {
  __builtin_amdgcn_global_load_lds(
      (const __attribute__((address_space(1))) void*)g,
      (__attribute__((address_space(3))) void*)l, 16, 0, 0);
}

// ---------------- router: logits -> softmax -> top2 -> weights ----------------
__global__ void router_kernel(const float* __restrict__ x,
                              const float* __restrict__ gw,
                              int* __restrict__ e12, float* __restrict__ w12,
                              int* __restrict__ cnt, float* __restrict__ probsum) {
  __shared__ float sProb[E_NUM];
  __shared__ int sCnt[E_NUM];
  int tid = threadIdx.x;
  if (tid < E_NUM) { sProb[tid] = 0.f; sCnt[tid] = 0; }
  __syncthreads();
  int g = tid >> 4, i = tid & 15;
  int t = blockIdx.x * 16 + g;
  float acc[E_NUM];
#pragma unroll
  for (int e = 0; e < E_NUM; e++) acc[e] = 0.f;
  const f32x4* x4 = (const f32x4*)(x + (size_t)t * D_DIM);
  const f32x4* g4 = (const f32x4*)gw;
  for (int jj = 0; jj < 16; jj++) {
    f32x4 xv = x4[i + 16 * jj];
    int jb = 4 * (i + 16 * jj);
#pragma unroll
    for (int r = 0; r < 4; r++) {
      float xs = xv[r];
#pragma unroll
      for (int e4 = 0; e4 < 4; e4++) {
        f32x4 gv = g4[(jb + r) * 4 + e4];
        acc[e4 * 4 + 0] += xs * gv[0];
        acc[e4 * 4 + 1] += xs * gv[1];
        acc[e4 * 4 + 2] += xs * gv[2];
        acc[e4 * 4 + 3] += xs * gv[3];
      }
    }
  }
#pragma unroll
  for (int e = 0; e < E_NUM; e++) {
    float v = acc[e];
    v += __shfl_down(v, 8, 16);
    v += __shfl_down(v, 4, 16);
    v += __shfl_down(v, 2, 16);
    v += __shfl_down(v, 1, 16);
    acc[e] = v;
  }
  if (i == 0) {
    float mx = acc[0];
#pragma unroll
    for (int e = 1; e < E_NUM; e++) mx = fmaxf(mx, acc[e]);
    float p[E_NUM]; float s = 0.f;
#pragma unroll
    for (int e = 0; e < E_NUM; e++) { p[e] = __expf(acc[e] - mx); s += p[e]; }
    float inv = 1.f / s;
#pragma unroll
    for (int e = 0; e < E_NUM; e++) p[e] *= inv;
    int e1 = 0; float p1 = p[0];
#pragma unroll
    for (int e = 1; e < E_NUM; e++) if (p[e] > p1) { p1 = p[e]; e1 = e; }
    int e2 = (e1 == 0) ? 1 : 0; float p2 = p[e2];
#pragma unroll
    for (int e = 0; e < E_NUM; e++) if (e != e1 && p[e] > p2) { p2 = p[e]; e2 = e; }
    float wsum = p1 + p2;
    e12[2 * t] = e1; e12[2 * t + 1] = e2;
    w12[2 * t] = p1 / wsum; w12[2 * t + 1] = p2 / wsum;
#pragma unroll
    for (int e = 0; e < E_NUM; e++) atomicAdd(&sProb[e], p[e]);
    atomicAdd(&sCnt[e1], 1);
    atomicAdd(&sCnt[e2], 1);
  }
  __syncthreads();
  if (tid < E_NUM) {
    atomicAdd(&cnt[tid], sCnt[tid]);
    atomicAdd(&probsum[tid], sProb[tid]);
  }
}

__global__ void prefix_kernel(const int* __restrict__ cnt, int* __restrict__ offsets,
                              const float* __restrict__ probsum, float* __restrict__ aux_out) {
  if (threadIdx.x == 0) {
    int s = 0;
    for (int e = 0; e < E_NUM; e++) { offsets[e] = s; s += cnt[e]; }
    offsets[E_NUM] = s;
    float a = 0.f;
    for (int e = 0; e < E_NUM; e++) a += (float)cnt[e] * probsum[e];
    aux_out[0] = 0.01f * 16.f * a / (8192.f * 8192.f);
  }
}

__global__ void build_kernel(const int* __restrict__ e12, const float* __restrict__ w12,
                             const int* __restrict__ offsets, int* __restrict__ cursor,
                             int* __restrict__ tlist, float* __restrict__ wlist,
                             int* __restrict__ slot2) {
  int t = blockIdx.x * 256 + threadIdx.x;
  if (t >= T_TOKENS) return;
#pragma unroll
  for (int k = 0; k < 2; k++) {
    int e = e12[2 * t + k];
    int pos = atomicAdd(&cursor[e], 1);
    int idx = offsets[e] + pos;
    tlist[idx] = t;
    wlist[idx] = w12[2 * t + k];
    slot2[2 * t + k] = idx;   // inverse map: token -> its two slot rows
  }
}

__global__ void gather_kernel(const float* __restrict__ x, const int* __restrict__ tlist,
                              u16* __restrict__ Xe) {
  int r = blockIdx.x * 4 + (threadIdx.x >> 6);
  int lane = threadIdx.x & 63;
  int tok = tlist[r];
  const f32x4* src = (const f32x4*)(x + (size_t)tok * D_DIM);
  u32* dst = (u32*)(Xe + (size_t)r * D_DIM);
#pragma unroll
  for (int c = 0; c < 4; c++) {
    f32x4 v = src[lane + 64 * c];
    dst[(lane + 64 * c) * 2] = pack2(v[0], v[1]);
    dst[(lane + 64 * c) * 2 + 1] = pack2(v[2], v[3]);
  }
}

// ------------- weight transpose+convert v2: fp32 [E][K][N] -> bf16 [E][N][K] -------------
// 64k x 256n per block; 16 f32x4 loads/thread (ILP); u16 LDS tile stride 258
// (bank-clean); 16B s16x8 stores. Grid (K/64, N/256, E).
template <int K, int N>
__global__ __launch_bounds__(256) void transpose_kernel(const float* __restrict__ W,
                                                        u16* __restrict__ Wt) {
  __shared__ u16 tile[64][258];  // stride 258 u16 = 129 dwords == 1 mod 32
  int e = blockIdx.z;
  int k0 = blockIdx.x * 64;
  int n0 = blockIdx.y * 256;
  const float* Win = W + (size_t)e * K * N;
  u16* Wout = Wt + (size_t)e * N * K;
  int t = threadIdx.x;
  int r = t >> 4;          // 0..15
  int c4 = (t & 15) * 4;   // 0..60
#pragma unroll
  for (int rep = 0; rep < 4; rep++) {
    int k = r + rep * 16;
    const float* rowp = Win + (size_t)(k0 + k) * N + n0;
#pragma unroll
    for (int s = 0; s < 4; s++) {
      f32x4 v = *(const f32x4*)(rowp + s * 64 + c4);
      *(u32*)&tile[k][s * 64 + c4] = pack2(v[0], v[1]);
      *(u32*)&tile[k][s * 64 + c4 + 2] = pack2(v[2], v[3]);
    }
  }
  __syncthreads();
#pragma unroll
  for (int rep = 0; rep < 8; rep++) {
    int c = t + 256 * rep;       // 0..2047
    int n = c >> 3;              // 0..255
    int k8 = (c & 7) * 8;        // 0..56
    s16x8 o;
#pragma unroll
    for (int i = 0; i < 8; i++) o[i] = tile[k8 + i][n];
    *(s16x8*)(Wout + (size_t)(n0 + n) * K + k0 + k8) = o;
  }
}

// ------- fused G/U GEMM: H = silu(Xe@WgT) * (Xe@WuT) -------
// 256x128 tile, BK=64, 8 waves (4M x 2N), double-buffered LDS, counted vmcnt,
// phase-split MFMA clusters with setprio, XOR-swizzled LDS.  (unchanged, passing)
__global__ __launch_bounds__(512, 2) void gemm_gu_kernel(
    const u16* __restrict__ Abuf, const u16* __restrict__ Bg, const u16* __restrict__ Bu,
    u16* __restrict__ Hbuf,
    const int* __restrict__ cnt, const int* __restrict__ offsets) {
  int e = blockIdx.z;
  int Me = cnt[e];
  int m0 = blockIdx.y * 256;
  if (m0 >= Me) return;
  int n0 = blockIdx.x * 128;
  int rowBase = offsets[e];
  const u16* Bge = Bg + (size_t)e * I_DIM * D_DIM;
  const u16* Bue = Bu + (size_t)e * I_DIM * D_DIM;

  __shared__ u16 lds[65536];  // 128 KiB
  constexpr int A0 = 0, A1 = 16384;
  constexpr int Bg0 = 32768, Bg1 = 40960;
  constexpr int Bu0 = 49152, Bu1 = 57344;

  int tid = threadIdx.x;
  int lane = tid & 63;
  int wv = tid >> 6;           // 0..7
  int wm = wv >> 1;            // 0..3 (M quadrant, 64 rows each)
  int wn = wv & 1;             // 0..1 (N half, 64 cols each)
  int lrow = lane & 15, lq = lane >> 4;
  int swz = lrow & 7;          // read-side XOR

  f32x4 accg[4][4], accu[4][4];
#pragma unroll
  for (int a = 0; a < 4; a++)
#pragma unroll
    for (int b = 0; b < 4; b++) { accg[a][b] = (f32x4)0.f; accu[a][b] = (f32x4)0.f; }

  auto STAGE = [&](int kt, int b) {
    int k0 = kt << 6;
#pragma unroll
    for (int r = 0; r < 4; r++) {
      int c = tid + 512 * r;
      int row = c >> 3, slot = c & 7;
      int gr = m0 + row; gr = (gr < Me) ? gr : (Me - 1);
      const u16* src = Abuf + (size_t)(rowBase + gr) * D_DIM + k0 + ((slot ^ (row & 7)) << 3);
      async_load16(src, (void*)&lds[(b ? A1 : A0) + (wv * 64 + 512 * r) * 8]);
    }
#pragma unroll
    for (int r = 0; r < 2; r++) {
      int c = tid + 512 * r;
      int row = c >> 3, slot = c & 7;
      int col = k0 + ((slot ^ (row & 7)) << 3);
      int ldso = (wv * 64 + 512 * r) * 8;
      async_load16(Bge + (size_t)(n0 + row) * D_DIM + col, (void*)&lds[(b ? Bg1 : Bg0) + ldso]);
      async_load16(Bue + (size_t)(n0 + row) * D_DIM + col, (void*)&lds[(b ? Bu1 : Bu0) + ldso]);
    }
  };

  STAGE(0, 0);
  STAGE(1, 1);

  for (int kt = 0; kt < 16; kt++) {
    int cur = kt & 1;
    if (kt < 15) asm volatile("s_waitcnt vmcnt(8)");
    else         asm volatile("s_waitcnt vmcnt(0)");
    __builtin_amdgcn_s_barrier();
    __builtin_amdgcn_sched_barrier(0);

    const u16* As = lds + (cur ? A1 : A0);
    const u16* Bgs = lds + (cur ? Bg1 : Bg0);
    const u16* Bus = lds + (cur ? Bu1 : Bu0);

#pragma unroll
    for (int kh = 0; kh < 2; kh++) {
      s16x8 af[4], bb[4];
      int so = ((kh * 4 + lq) ^ swz) << 3;
#pragma unroll
      for (int fm = 0; fm < 4; fm++) {
        int row = wm * 64 + fm * 16 + lrow;
        af[fm] = *(const s16x8*)&As[row * 64 + so];
      }
#pragma unroll
      for (int fn = 0; fn < 4; fn++) {
        int row = wn * 64 + fn * 16 + lrow;
        bb[fn] = *(const s16x8*)&Bgs[row * 64 + so];
      }
      __builtin_amdgcn_s_barrier();
      __builtin_amdgcn_s_setprio(1);
#pragma unroll
      for (int fm = 0; fm < 4; fm++)
#pragma unroll
        for (int fn = 0; fn < 4; fn++)
          accg[fm][fn] = __builtin_amdgcn_mfma_f32_16x16x32_bf16(af[fm], bb[fn], accg[fm][fn], 0, 0, 0);
      __builtin_amdgcn_s_setprio(0);
      __builtin_amdgcn_s_barrier();
#pragma unroll
      for (int fn = 0; fn < 4; fn++) {
        int row = wn * 64 + fn * 16 + lrow;
        bb[fn] = *(const s16x8*)&Bus[row * 64 + so];
      }
      __builtin_amdgcn_s_barrier();
      __builtin_amdgcn_s_setprio(1);
#pragma unroll
      for (int fm = 0; fm < 4; fm++)
#pragma unroll
        for (int fn = 0; fn < 4; fn++)
          accu[fm][fn] = __builtin_amdgcn_mfma_f32_16x16x32_bf16(af[fm], bb[fn], accu[fm][fn], 0, 0, 0);
      __builtin_amdgcn_s_setprio(0);
      __builtin_amdgcn_s_barrier();
    }

    __builtin_amdgcn_sched_barrier(0);
    if (kt + 2 < 16) STAGE(kt + 2, cur);
  }

  // C/D layout: col=lane&15, row=(lane>>4)*4+reg
#pragma unroll
  for (int fm = 0; fm < 4; fm++) {
#pragma unroll
    for (int i = 0; i < 4; i++) {
      int m = m0 + wm * 64 + fm * 16 + lq * 4 + i;
      if (m >= Me) continue;
      size_t arow = (size_t)(rowBase + m);
#pragma unroll
      for (int fn = 0; fn < 4; fn++) {
        int col = n0 + wn * 64 + fn * 16 + lrow;
        float g = accg[fm][fn][i];
        float u = accu[fm][fn][i];
        float h = (g / (1.f + __expf(-g))) * u;
        Hbuf[arow * I_DIM + col] = f2bf(h);
      }
    }
  }
}

// ------- down GEMM v2: Y[slot] = w * (H @ WdT) -------
// 256x128 tile, BK=64, 8 waves (4M x 2N), double-buffered LDS, counted vmcnt(6),
// 2x16-MFMA setprio clusters per K-tile, XOR-swizzled LDS, plain fp32 stores.
__global__ __launch_bounds__(512, 2) void gemm_down_kernel(
    const u16* __restrict__ Abuf, const u16* __restrict__ Bd, float* __restrict__ Y,
    const int* __restrict__ cnt, const int* __restrict__ offsets,
    const float* __restrict__ wlist) {
  int e = blockIdx.z;
  int Me = cnt[e];
  int m0 = blockIdx.y * 256;
  if (m0 >= Me) return;
  int n0 = blockIdx.x * 128;
  int rowBase = offsets[e];
  const u16* Bde = Bd + (size_t)e * D_DIM * I_DIM;

  __shared__ u16 lds[49152];  // 96 KiB: A 2x16384, B 2x8192
  constexpr int A0 = 0, A1 = 16384;
  constexpr int B0 = 32768, B1 = 40960;

  int tid = threadIdx.x;
  int lane = tid & 63;
  int wv = tid >> 6;
  int wm = wv >> 1;            // 0..3
  int wn = wv & 1;             // 0..1
  int lrow = lane & 15, lq = lane >> 4;
  int swz = lrow & 7;

  f32x4 acc[4][4];
#pragma unroll
  for (int a = 0; a < 4; a++)
#pragma unroll
    for (int b = 0; b < 4; b++) acc[a][b] = (f32x4)0.f;

  auto STAGE = [&](int kt, int b) {
    int k0 = kt << 6;
#pragma unroll
    for (int r = 0; r < 4; r++) {
      int c = tid + 512 * r;
      int row = c >> 3, slot = c & 7;
      int gr = m0 + row; gr = (gr < Me) ? gr : (Me - 1);
      const u16* src = Abuf + (size_t)(rowBase + gr) * I_DIM + k0 + ((slot ^ (row & 7)) << 3);
      async_load16(src, (void*)&lds[(b ? A1 : A0) + (wv * 64 + 512 * r) * 8]);
    }
    {
      int r = 0;
#pragma unroll
      for (r = 0; r < 2; r++) {
        int c = tid + 512 * r;
        int row = c >> 3, slot = c & 7;
        int col = k0 + ((slot ^ (row & 7)) << 3);
        async_load16(Bde + (size_t)(n0 + row) * I_DIM + col,
                     (void*)&lds[(b ? B1 : B0) + (wv * 64 + 512 * r) * 8]);
      }
    }
  };

  STAGE(0, 0);
  STAGE(1, 1);

  // I_DIM/64 = 44 K-tiles
  for (int kt = 0; kt < 44; kt++) {
    int cur = kt & 1;
    if (kt < 43) asm volatile("s_waitcnt vmcnt(6)");
    else         asm volatile("s_waitcnt vmcnt(0)");
    __builtin_amdgcn_s_barrier();
    __builtin_amdgcn_sched_barrier(0);

    const u16* As = lds + (cur ? A1 : A0);
    const u16* Bs = lds + (cur ? B1 : B0);

#pragma unroll
    for (int kh = 0; kh < 2; kh++) {
      s16x8 af[4], bb[4];
      int so = ((kh * 4 + lq) ^ swz) << 3;
#pragma unroll
      for (int fm = 0; fm < 4; fm++) {
        int row = wm * 64 + fm * 16 + lrow;
        af[fm] = *(const s16x8*)&As[row * 64 + so];
      }
#pragma unroll
      for (int fn = 0; fn < 4; fn++) {
        int row = wn * 64 + fn * 16 + lrow;
        bb[fn] = *(const s16x8*)&Bs[row * 64 + so];
      }
      __builtin_amdgcn_s_barrier();
      __builtin_amdgcn_s_setprio(1);
#pragma unroll
      for (int fm = 0; fm < 4; fm++)
#pragma unroll
        for (int fn = 0; fn < 4; fn++)
          acc[fm][fn] = __builtin_amdgcn_mfma_f32_16x16x32_bf16(af[fm], bb[fn], acc[fm][fn], 0, 0, 0);
      __builtin_amdgcn_s_setprio(0);
      __builtin_amdgcn_s_barrier();
    }

    __builtin_amdgcn_sched_barrier(0);
    if (kt + 2 < 44) STAGE(kt + 2, cur);
  }

#pragma unroll
  for (int fm = 0; fm < 4; fm++) {
#pragma unroll
    for (int i = 0; i < 4; i++) {
      int m = m0 + wm * 64 + fm * 16 + lq * 4 + i;
      if (m >= Me) continue;
      size_t arow = (size_t)(rowBase + m);
      float w = wlist[arow];
#pragma unroll
      for (int fn = 0; fn < 4; fn++) {
        int col = n0 + wn * 64 + fn * 16 + lrow;
        Y[arow * D_DIM + col] = acc[fm][fn][i] * w;
      }
    }
  }
}

// ------- combine: out[t] = Y[slot1(t)] + Y[slot2(t)] (weights folded into Y) -------
__global__ __launch_bounds__(256) void combine_kernel(
    const float* __restrict__ Y, const int* __restrict__ slot2,
    float* __restrict__ out) {
  int t = blockIdx.x;
  int tid = threadIdx.x;
  int s1 = slot2[2 * t];
  int s2 = slot2[2 * t + 1];
  const f32x4* y1 = (const f32x4*)(Y + (size_t)s1 * D_DIM);
  const f32x4* y2 = (const f32x4*)(Y + (size_t)s2 * D_DIM);
  f32x4* o = (f32x4*)(out + (size_t)t * D_DIM);
  o[tid] = y1[tid] + y2[tid];
}

// ws layout (bytes):
//   0: cnt[16] | 64: cursor[16] | 128: probsum[16] | 192: offsets[17]
//   512: e12 | 66048: w12 | 131584: tlist | 197120: wlist | 262656: slot2[16384]
//   1 MiB: Xe bf16 [16384][1024]            (32 MiB)
//   34603008: H bf16 [16384][2816]          (88 MiB)
//   134217728: WtA bf16 [16][2816][1024]    (88 MiB)  Wg_t, later Wd_t
//   234881024: WtB bf16 [16][2816][1024]    (88 MiB)  Wu_t, later Y fp32 [16384][1024] (64 MiB)
extern "C" void kernel_launch(void* const* d_in, const int* in_sizes, int n_in,
                              void* d_out, int out_size, void* d_ws, size_t ws_size,
                              hipStream_t stream) {
  const float* x  = (const float*)d_in[0];
  const float* gw = (const float*)d_in[1];
  const float* Wg = (const float*)d_in[2];
  const float* Wu = (const float*)d_in[3];
  const float* Wd = (const float*)d_in[4];
  float* outf = (float*)d_out;
  char* ws = (char*)d_ws;
  int*   cnt     = (int*)(ws + 0);
  int*   cursor  = (int*)(ws + 64);
  float* probsum = (float*)(ws + 128);
  int*   offsets = (int*)(ws + 192);
  int*   e12     = (int*)(ws + 512);
  float* w12     = (float*)(ws + 66048);
  int*   tlist   = (int*)(ws + 131584);
  float* wlist   = (float*)(ws + 197120);
  int*   slot2   = (int*)(ws + 262656);
  u16*   Xe      = (u16*)(ws + (1 << 20));
  u16*   H       = (u16*)(ws + 34603008);
  u16*   WtA     = (u16*)(ws + 134217728);
  u16*   WtB     = (u16*)(ws + 234881024);
  float* Y       = (float*)(ws + 234881024);  // reuses WtB region after gu

  hipMemsetAsync(d_ws, 0, 512, stream);

  router_kernel<<<512, 256, 0, stream>>>(x, gw, e12, w12, cnt, probsum);
  prefix_kernel<<<1, 64, 0, stream>>>(cnt, offsets, probsum, outf + (size_t)(T_TOKENS * D_DIM));
  build_kernel<<<32, 256, 0, stream>>>(e12, w12, offsets, cursor, tlist, wlist, slot2);
  gather_kernel<<<4096, 256, 0, stream>>>(x, tlist, Xe);

  // Wg: [E][1024][2816] -> WtA [E][2816][1024];  Wu -> WtB
  transpose_kernel<D_DIM, I_DIM><<<dim3(16, 11, E_NUM), 256, 0, stream>>>(Wg, WtA);
  transpose_kernel<D_DIM, I_DIM><<<dim3(16, 11, E_NUM), 256, 0, stream>>>(Wu, WtB);

  gemm_gu_kernel<<<dim3(22, 32, E_NUM), 512, 0, stream>>>(Xe, WtA, WtB, H, cnt, offsets);

  // Wd: [E][2816][1024] -> WtA [E][1024][2816]
  transpose_kernel<I_DIM, D_DIM><<<dim3(44, 4, E_NUM), 256, 0, stream>>>(Wd, WtA);

  // Y (in old WtB region) <- w * (H @ Wd^T); no atomics
  gemm_down_kernel<<<dim3(8, 32, E_NUM), 512, 0, stream>>>(H, WtA, Y, cnt, offsets, wlist);

  combine_kernel<<<T_TOKENS, 256, 0, stream>>>(Y, slot2, outf);
}

// Round 5
// 1090.490 us; speedup vs baseline: 1.0401x; 1.0401x over previous
//
#include <hip/hip_runtime.h>
#include <stdint.h>

#define T_TOKENS 8192
#define D_DIM 1024
#define I_DIM 2816
#define E_NUM 16
#define N_SLOTS 16384

typedef float f32x4 __attribute__((ext_vector_type(4)));
typedef short s16x8 __attribute__((ext_vector_type(8)));
typedef short s16x4 __attribute__((ext_vector_type(4)));
typedef unsigned short u16;
typedef unsigned int u32;

__device__ __forceinline__ u16 f2bf(float f) {
  u32 u = __builtin_bit_cast(u32, f);
  u = (u + 0x7FFFu + ((u >> 16) & 1u)) >> 16;
  return (u16)u;
}
__device__ __forceinline__ u32 pack2(float a, float b) {
  return (u32)f2bf(a) | ((u32)f2bf(b) << 16);
}
__device__ __forceinline__ void async_load16(const void* g, void* l) {
  __builtin_amdgcn_global_load_lds(
      (const __attribute__((address_space(1))) void*)g,
      (__attribute__((address_space(3))) void*)l, 16, 0, 0);
}

// ---------------- router: logits -> softmax -> top2 -> weights ----------------
__global__ void router_kernel(const float* __restrict__ x,
                              const float* __restrict__ gw,
                              int* __restrict__ e12, float* __restrict__ w12,
                              int* __restrict__ cnt, float* __restrict__ probsum) {
  __shared__ float sProb[E_NUM];
  __shared__ int sCnt[E_NUM];
  int tid = threadIdx.x;
  if (tid < E_NUM) { sProb[tid] = 0.f; sCnt[tid] = 0; }
  __syncthreads();
  int g = tid >> 4, i = tid & 15;
  int t = blockIdx.x * 16 + g;
  float acc[E_NUM];
#pragma unroll
  for (int e = 0; e < E_NUM; e++) acc[e] = 0.f;
  const f32x4* x4 = (const f32x4*)(x + (size_t)t * D_DIM);
  const f32x4* g4 = (const f32x4*)gw;
  for (int jj = 0; jj < 16; jj++) {
    f32x4 xv = x4[i + 16 * jj];
    int jb = 4 * (i + 16 * jj);
#pragma unroll
    for (int r = 0; r < 4; r++) {
      float xs = xv[r];
#pragma unroll
      for (int e4 = 0; e4 < 4; e4++) {
        f32x4 gv = g4[(jb + r) * 4 + e4];
        acc[e4 * 4 + 0] += xs * gv[0];
        acc[e4 * 4 + 1] += xs * gv[1];
        acc[e4 * 4 + 2] += xs * gv[2];
        acc[e4 * 4 + 3] += xs * gv[3];
      }
    }
  }
#pragma unroll
  for (int e = 0; e < E_NUM; e++) {
    float v = acc[e];
    v += __shfl_down(v, 8, 16);
    v += __shfl_down(v, 4, 16);
    v += __shfl_down(v, 2, 16);
    v += __shfl_down(v, 1, 16);
    acc[e] = v;
  }
  if (i == 0) {
    float mx = acc[0];
#pragma unroll
    for (int e = 1; e < E_NUM; e++) mx = fmaxf(mx, acc[e]);
    float p[E_NUM]; float s = 0.f;
#pragma unroll
    for (int e = 0; e < E_NUM; e++) { p[e] = __expf(acc[e] - mx); s += p[e]; }
    float inv = 1.f / s;
#pragma unroll
    for (int e = 0; e < E_NUM; e++) p[e] *= inv;
    int e1 = 0; float p1 = p[0];
#pragma unroll
    for (int e = 1; e < E_NUM; e++) if (p[e] > p1) { p1 = p[e]; e1 = e; }
    int e2 = (e1 == 0) ? 1 : 0; float p2 = p[e2];
#pragma unroll
    for (int e = 0; e < E_NUM; e++) if (e != e1 && p[e] > p2) { p2 = p[e]; e2 = e; }
    float wsum = p1 + p2;
    e12[2 * t] = e1; e12[2 * t + 1] = e2;
    w12[2 * t] = p1 / wsum; w12[2 * t + 1] = p2 / wsum;
#pragma unroll
    for (int e = 0; e < E_NUM; e++) atomicAdd(&sProb[e], p[e]);
    atomicAdd(&sCnt[e1], 1);
    atomicAdd(&sCnt[e2], 1);
  }
  __syncthreads();
  if (tid < E_NUM) {
    atomicAdd(&cnt[tid], sCnt[tid]);
    atomicAdd(&probsum[tid], sProb[tid]);
  }
}

__global__ void prefix_kernel(const int* __restrict__ cnt, int* __restrict__ offsets,
                              const float* __restrict__ probsum, float* __restrict__ aux_out) {
  if (threadIdx.x == 0) {
    int s = 0;
    for (int e = 0; e < E_NUM; e++) { offsets[e] = s; s += cnt[e]; }
    offsets[E_NUM] = s;
    float a = 0.f;
    for (int e = 0; e < E_NUM; e++) a += (float)cnt[e] * probsum[e];
    aux_out[0] = 0.01f * 16.f * a / (8192.f * 8192.f);
  }
}

__global__ void build_kernel(const int* __restrict__ e12, const float* __restrict__ w12,
                             const int* __restrict__ offsets, int* __restrict__ cursor,
                             int* __restrict__ tlist, float* __restrict__ wlist,
                             int* __restrict__ slot2) {
  int t = blockIdx.x * 256 + threadIdx.x;
  if (t >= T_TOKENS) return;
#pragma unroll
  for (int k = 0; k < 2; k++) {
    int e = e12[2 * t + k];
    int pos = atomicAdd(&cursor[e], 1);
    int idx = offsets[e] + pos;
    tlist[idx] = t;
    wlist[idx] = w12[2 * t + k];
    slot2[2 * t + k] = idx;   // inverse map: token -> its two slot rows
  }
}

__global__ void gather_kernel(const float* __restrict__ x, const int* __restrict__ tlist,
                              u16* __restrict__ Xe) {
  int r = blockIdx.x * 4 + (threadIdx.x >> 6);
  int lane = threadIdx.x & 63;
  int tok = tlist[r];
  const f32x4* src = (const f32x4*)(x + (size_t)tok * D_DIM);
  u32* dst = (u32*)(Xe + (size_t)r * D_DIM);
#pragma unroll
  for (int c = 0; c < 4; c++) {
    f32x4 v = src[lane + 64 * c];
    dst[(lane + 64 * c) * 2] = pack2(v[0], v[1]);
    dst[(lane + 64 * c) * 2 + 1] = pack2(v[2], v[3]);
  }
}

// ------------- weight transpose+convert v2: fp32 [E][K][N] -> bf16 [E][N][K] -------------
template <int K, int N>
__global__ __launch_bounds__(256) void transpose_kernel(const float* __restrict__ W,
                                                        u16* __restrict__ Wt) {
  __shared__ u16 tile[64][258];  // stride 258 u16 = 129 dwords == 1 mod 32
  int e = blockIdx.z;
  int k0 = blockIdx.x * 64;
  int n0 = blockIdx.y * 256;
  const float* Win = W + (size_t)e * K * N;
  u16* Wout = Wt + (size_t)e * N * K;
  int t = threadIdx.x;
  int r = t >> 4;          // 0..15
  int c4 = (t & 15) * 4;   // 0..60
#pragma unroll
  for (int rep = 0; rep < 4; rep++) {
    int k = r + rep * 16;
    const float* rowp = Win + (size_t)(k0 + k) * N + n0;
#pragma unroll
    for (int s = 0; s < 4; s++) {
      f32x4 v = *(const f32x4*)(rowp + s * 64 + c4);
      *(u32*)&tile[k][s * 64 + c4] = pack2(v[0], v[1]);
      *(u32*)&tile[k][s * 64 + c4 + 2] = pack2(v[2], v[3]);
    }
  }
  __syncthreads();
#pragma unroll
  for (int rep = 0; rep < 8; rep++) {
    int c = t + 256 * rep;       // 0..2047
    int n = c >> 3;              // 0..255
    int k8 = (c & 7) * 8;        // 0..56
    s16x8 o;
#pragma unroll
    for (int i = 0; i < 8; i++) o[i] = tile[k8 + i][n];
    *(s16x8*)(Wout + (size_t)(n0 + n) * K + k0 + k8) = o;
  }
}

// ------- fused G/U GEMM (m97 structure): 128x128 tile, BK=64, 4 waves, -------
// single-buffered LDS (48 KiB -> 2 blocks/CU), plain __syncthreads(),
// XOR-swizzled LDS (pre-swizzled global source + swizzled ds_read).
__global__ __launch_bounds__(256, 2) void gemm_gu_kernel(
    const u16* __restrict__ Abuf, const u16* __restrict__ Bg, const u16* __restrict__ Bu,
    u16* __restrict__ Hbuf,
    const int* __restrict__ cnt, const int* __restrict__ offsets) {
  int e = blockIdx.z;
  int Me = cnt[e];
  int m0 = blockIdx.y * 128;
  if (m0 >= Me) return;
  int n0 = blockIdx.x * 128;
  int rowBase = offsets[e];
  const u16* Bge = Bg + (size_t)e * I_DIM * D_DIM;
  const u16* Bue = Bu + (size_t)e * I_DIM * D_DIM;

  __shared__ u16 Ash[128 * 64];
  __shared__ u16 Bgsh[128 * 64];
  __shared__ u16 Bush[128 * 64];

  int tid = threadIdx.x;
  int lane = tid & 63;
  int wv = tid >> 6;           // 0..3
  int wm = wv >> 1;            // 0..1 (M half, 64 rows)
  int wn = wv & 1;             // 0..1 (N half, 64 cols)
  int lrow = lane & 15, lq = lane >> 4;
  int swz = lrow & 7;

  f32x4 accg[4][4], accu[4][4];
#pragma unroll
  for (int a = 0; a < 4; a++)
#pragma unroll
    for (int b = 0; b < 4; b++) { accg[a][b] = (f32x4)0.f; accu[a][b] = (f32x4)0.f; }

  for (int kt = 0; kt < 16; kt++) {
    int k0 = kt << 6;
    // stage A,Bg,Bu: each 128 rows x 8 slots(16B) = 1024 chunks / 256 thr
#pragma unroll
    for (int r = 0; r < 4; r++) {
      int c = tid + 256 * r;
      int row = c >> 3, slot = c & 7;
      int co = (slot ^ (row & 7)) << 3;     // pre-swizzled source column (u16)
      int ldso = (wv * 64 + 256 * r) * 8;   // linear LDS dest (u16)
      int gr = m0 + row; gr = (gr < Me) ? gr : (Me - 1);
      async_load16(Abuf + (size_t)(rowBase + gr) * D_DIM + k0 + co, &Ash[ldso]);
      async_load16(Bge + (size_t)(n0 + row) * D_DIM + k0 + co, &Bgsh[ldso]);
      async_load16(Bue + (size_t)(n0 + row) * D_DIM + k0 + co, &Bush[ldso]);
    }
    __syncthreads();
#pragma unroll
    for (int kh = 0; kh < 2; kh++) {
      s16x8 af[4], bg[4], bu[4];
      int so = ((kh * 4 + lq) ^ swz) << 3;  // swizzled read slot
#pragma unroll
      for (int f = 0; f < 4; f++) {
        af[f] = *(const s16x8*)&Ash[(wm * 64 + f * 16 + lrow) * 64 + so];
        bg[f] = *(const s16x8*)&Bgsh[(wn * 64 + f * 16 + lrow) * 64 + so];
        bu[f] = *(const s16x8*)&Bush[(wn * 64 + f * 16 + lrow) * 64 + so];
      }
#pragma unroll
      for (int fm = 0; fm < 4; fm++)
#pragma unroll
        for (int fn = 0; fn < 4; fn++) {
          accg[fm][fn] = __builtin_amdgcn_mfma_f32_16x16x32_bf16(af[fm], bg[fn], accg[fm][fn], 0, 0, 0);
          accu[fm][fn] = __builtin_amdgcn_mfma_f32_16x16x32_bf16(af[fm], bu[fn], accu[fm][fn], 0, 0, 0);
        }
    }
    __syncthreads();
  }

  // C/D layout: col=lane&15, row=(lane>>4)*4+reg
#pragma unroll
  for (int fm = 0; fm < 4; fm++) {
#pragma unroll
    for (int i = 0; i < 4; i++) {
      int m = m0 + wm * 64 + fm * 16 + lq * 4 + i;
      if (m >= Me) continue;
      size_t arow = (size_t)(rowBase + m);
#pragma unroll
      for (int fn = 0; fn < 4; fn++) {
        int col = n0 + wn * 64 + fn * 16 + lrow;
        float g = accg[fm][fn][i];
        float u = accu[fm][fn][i];
        float h = (g / (1.f + __expf(-g))) * u;
        Hbuf[arow * I_DIM + col] = f2bf(h);
      }
    }
  }
}

// ------- down GEMM (m97 structure): Y[slot] = w * (H @ WdT) -------
// 128x128 tile, BK=64, 4 waves, single-buffered 32 KiB LDS -> 3 blocks/CU.
__global__ __launch_bounds__(256, 3) void gemm_down_kernel(
    const u16* __restrict__ Abuf, const u16* __restrict__ Bd, float* __restrict__ Y,
    const int* __restrict__ cnt, const int* __restrict__ offsets,
    const float* __restrict__ wlist) {
  int e = blockIdx.z;
  int Me = cnt[e];
  int m0 = blockIdx.y * 128;
  if (m0 >= Me) return;
  int n0 = blockIdx.x * 128;
  int rowBase = offsets[e];
  const u16* Bde = Bd + (size_t)e * D_DIM * I_DIM;

  __shared__ u16 Ash[128 * 64];
  __shared__ u16 Bsh[128 * 64];

  int tid = threadIdx.x;
  int lane = tid & 63;
  int wv = tid >> 6;
  int wm = wv >> 1;
  int wn = wv & 1;
  int lrow = lane & 15, lq = lane >> 4;
  int swz = lrow & 7;

  f32x4 acc[4][4];
#pragma unroll
  for (int a = 0; a < 4; a++)
#pragma unroll
    for (int b = 0; b < 4; b++) acc[a][b] = (f32x4)0.f;

  // I_DIM/64 = 44 K-tiles
  for (int kt = 0; kt < 44; kt++) {
    int k0 = kt << 6;
#pragma unroll
    for (int r = 0; r < 4; r++) {
      int c = tid + 256 * r;
      int row = c >> 3, slot = c & 7;
      int co = (slot ^ (row & 7)) << 3;
      int ldso = (wv * 64 + 256 * r) * 8;
      int gr = m0 + row; gr = (gr < Me) ? gr : (Me - 1);
      async_load16(Abuf + (size_t)(rowBase + gr) * I_DIM + k0 + co, &Ash[ldso]);
      async_load16(Bde + (size_t)(n0 + row) * I_DIM + k0 + co, &Bsh[ldso]);
    }
    __syncthreads();
#pragma unroll
    for (int kh = 0; kh < 2; kh++) {
      s16x8 af[4], bb[4];
      int so = ((kh * 4 + lq) ^ swz) << 3;
#pragma unroll
      for (int f = 0; f < 4; f++) {
        af[f] = *(const s16x8*)&Ash[(wm * 64 + f * 16 + lrow) * 64 + so];
        bb[f] = *(const s16x8*)&Bsh[(wn * 64 + f * 16 + lrow) * 64 + so];
      }
#pragma unroll
      for (int fm = 0; fm < 4; fm++)
#pragma unroll
        for (int fn = 0; fn < 4; fn++)
          acc[fm][fn] = __builtin_amdgcn_mfma_f32_16x16x32_bf16(af[fm], bb[fn], acc[fm][fn], 0, 0, 0);
    }
    __syncthreads();
  }

#pragma unroll
  for (int fm = 0; fm < 4; fm++) {
#pragma unroll
    for (int i = 0; i < 4; i++) {
      int m = m0 + wm * 64 + fm * 16 + lq * 4 + i;
      if (m >= Me) continue;
      size_t arow = (size_t)(rowBase + m);
      float w = wlist[arow];
#pragma unroll
      for (int fn = 0; fn < 4; fn++) {
        int col = n0 + wn * 64 + fn * 16 + lrow;
        Y[arow * D_DIM + col] = acc[fm][fn][i] * w;
      }
    }
  }
}

// ------- combine: out[t] = Y[slot1(t)] + Y[slot2(t)] (weights folded into Y) -------
__global__ __launch_bounds__(256) void combine_kernel(
    const float* __restrict__ Y, const int* __restrict__ slot2,
    float* __restrict__ out) {
  int t = blockIdx.x;
  int tid = threadIdx.x;
  int s1 = slot2[2 * t];
  int s2 = slot2[2 * t + 1];
  const f32x4* y1 = (const f32x4*)(Y + (size_t)s1 * D_DIM);
  const f32x4* y2 = (const f32x4*)(Y + (size_t)s2 * D_DIM);
  f32x4* o = (f32x4*)(out + (size_t)t * D_DIM);
  o[tid] = y1[tid] + y2[tid];
}

// ws layout (bytes):
//   0: cnt[16] | 64: cursor[16] | 128: probsum[16] | 192: offsets[17]
//   512: e12 | 66048: w12 | 131584: tlist | 197120: wlist | 262656: slot2[16384]
//   1 MiB: Xe bf16 [16384][1024]            (32 MiB)
//   34603008: H bf16 [16384][2816]          (88 MiB)
//   134217728: WtA bf16 [16][2816][1024]    (88 MiB)  Wg_t, later Wd_t
//   234881024: WtB bf16 [16][2816][1024]    (88 MiB)  Wu_t, later Y fp32 [16384][1024] (64 MiB)
extern "C" void kernel_launch(void* const* d_in, const int* in_sizes, int n_in,
                              void* d_out, int out_size, void* d_ws, size_t ws_size,
                              hipStream_t stream) {
  const float* x  = (const float*)d_in[0];
  const float* gw = (const float*)d_in[1];
  const float* Wg = (const float*)d_in[2];
  const float* Wu = (const float*)d_in[3];
  const float* Wd = (const float*)d_in[4];
  float* outf = (float*)d_out;
  char* ws = (char*)d_ws;
  int*   cnt     = (int*)(ws + 0);
  int*   cursor  = (int*)(ws + 64);
  float* probsum = (float*)(ws + 128);
  int*   offsets = (int*)(ws + 192);
  int*   e12     = (int*)(ws + 512);
  float* w12     = (float*)(ws + 66048);
  int*   tlist   = (int*)(ws + 131584);
  float* wlist   = (float*)(ws + 197120);
  int*   slot2   = (int*)(ws + 262656);
  u16*   Xe      = (u16*)(ws + (1 << 20));
  u16*   H       = (u16*)(ws + 34603008);
  u16*   WtA     = (u16*)(ws + 134217728);
  u16*   WtB     = (u16*)(ws + 234881024);
  float* Y       = (float*)(ws + 234881024);  // reuses WtB region after gu

  hipMemsetAsync(d_ws, 0, 512, stream);

  router_kernel<<<512, 256, 0, stream>>>(x, gw, e12, w12, cnt, probsum);
  prefix_kernel<<<1, 64, 0, stream>>>(cnt, offsets, probsum, outf + (size_t)(T_TOKENS * D_DIM));
  build_kernel<<<32, 256, 0, stream>>>(e12, w12, offsets, cursor, tlist, wlist, slot2);
  gather_kernel<<<4096, 256, 0, stream>>>(x, tlist, Xe);

  // Wg: [E][1024][2816] -> WtA [E][2816][1024];  Wu -> WtB
  transpose_kernel<D_DIM, I_DIM><<<dim3(16, 11, E_NUM), 256, 0, stream>>>(Wg, WtA);
  transpose_kernel<D_DIM, I_DIM><<<dim3(16, 11, E_NUM), 256, 0, stream>>>(Wu, WtB);

  gemm_gu_kernel<<<dim3(22, 64, E_NUM), 256, 0, stream>>>(Xe, WtA, WtB, H, cnt, offsets);

  // Wd: [E][2816][1024] -> WtA [E][1024][2816]
  transpose_kernel<I_DIM, D_DIM><<<dim3(44, 4, E_NUM), 256, 0, stream>>>(Wd, WtA);

  // Y (in old WtB region) <- w * (H @ Wd^T); no atomics
  gemm_down_kernel<<<dim3(8, 64, E_NUM), 256, 0, stream>>>(H, WtA, Y, cnt, offsets, wlist);

  combine_kernel<<<T_TOKENS, 256, 0, stream>>>(Y, slot2, outf);
}